// Round 3
// baseline (245.639 us; speedup 1.0000x reference)
//
#include <hip/hip_runtime.h>
#include <stdint.h>

#define IN_DIM  32768
#define OUT_DIM 32768
#define BATCH   1024
#define NT      1024
#define ITER    (OUT_DIM / 4 / NT)   // 8 compute iters (4 outputs x 2 rows each)
#define SITER   (IN_DIM / 4 / NT)    // 8 stage iters (4 dims x 2 rows each)
#define RPB     2                    // rows per block, dim-interleaved in LDS
#define GRID    (BATCH / RPB)        // 512 blocks, 1 resident per CU (128 KiB LDS)
#define LDS_BYTES (IN_DIM * 4)       // word d = (fp16 row0[d], fp16 row1[d])

typedef float  fvec4 __attribute__((ext_vector_type(4)));
typedef __fp16 h2    __attribute__((ext_vector_type(2)));   // matches cvt_pkrtz return

__device__ __forceinline__ uint32_t pack2_f16(float lo, float hi) {
    h2 h = __builtin_amdgcn_cvt_pkrtz(lo, hi);   // lo->elem0, hi->elem1 (RTZ)
    return __builtin_bit_cast(uint32_t, h);
}
__device__ __forceinline__ uint32_t ldw(const uint32_t* base, uint32_t byteoff) {
    return *(const uint32_t*)((const char*)base + byteoff);
}
// packed select for both rows at once: flag ? 1-v : v  (fp16 pair)
__device__ __forceinline__ uint32_t sel2(uint32_t flag, uint32_t w) {
    h2 v = __builtin_bit_cast(h2, w);
    h2 one; one.x = (__fp16)1.0f; one.y = (__fp16)1.0f;
    h2 r = one - v;                                     // v_pk_add_f16 (neg mod)
    return flag ? __builtin_bit_cast(uint32_t, r) : w;  // one v_cndmask_b32
}

// packed layout: low16 = (idx_a<<1) | flagA ; high16 = (idx_b<<1) | flagB
__global__ void pack_meta(const int* __restrict__ idx_a,
                          const int* __restrict__ idx_b,
                          const float* __restrict__ logits,
                          uint32_t* __restrict__ packed) {
    int j = blockIdx.x * blockDim.x + threadIdx.x;
    if (j >= OUT_DIM) return;
    uint32_t ia = (((uint32_t)idx_a[j]) << 1) & 0xFFFFu;
    uint32_t ib = (((uint32_t)idx_b[j]) << 1) & 0xFFFFu;
    if (logits[2 * j + 0] > 0.0f) ia |= 1u;   // sigmoid(l)>0.5 <=> l>0
    if (logits[2 * j + 1] > 0.0f) ib |= 1u;
    packed[j] = ia | (ib << 16);
}

// Two rows per block, dim-interleaved fp16 in 128 KiB LDS:
// one ds_read_b32 at byte offset 4*idx serves the gather for BOTH rows.
// Halves gather instrs (1.05M -> 524K wave-instrs), conflicts, and meta loads.
__global__ __launch_bounds__(NT, 4) void logic_gather(
        const float* __restrict__ x,
        const uint32_t* __restrict__ packed,
        float* __restrict__ out) {
    extern __shared__ __align__(16) uint32_t rowi[];   // [IN_DIM] packed pairs
    const int t  = threadIdx.x;
    const int r0 = blockIdx.x;
    const int r1 = r0 + GRID;

    // ---- stage both rows, interleaved (coalesced float4 loads, b128 LDS writes)
    {
        const float4* __restrict__ xr0 = (const float4*)(x + (size_t)r0 * IN_DIM);
        const float4* __restrict__ xr1 = (const float4*)(x + (size_t)r1 * IN_DIM);
        uint4* __restrict__ row128 = (uint4*)rowi;
#pragma unroll
        for (int s = 0; s < SITER; ++s) {
            int e4 = s * NT + t;
            float4 v0 = xr0[e4];
            float4 v1 = xr1[e4];
            uint4 w;
            w.x = pack2_f16(v0.x, v1.x);
            w.y = pack2_f16(v0.y, v1.y);
            w.z = pack2_f16(v0.z, v1.z);
            w.w = pack2_f16(v0.w, v1.w);
            row128[e4] = w;
        }
    }

    // ---- preload ALL meta into registers before the barrier
    const uint4* __restrict__ pk = (const uint4*)packed;
    uint4 p[ITER];
#pragma unroll
    for (int i = 0; i < ITER; ++i) p[i] = pk[i * NT + t];

    __syncthreads();

    fvec4* __restrict__ o0 = (fvec4*)(out + (size_t)r0 * OUT_DIM);
    fvec4* __restrict__ o1 = (fvec4*)(out + (size_t)r1 * OUT_DIM);

#pragma unroll
    for (int i = 0; i < ITER; ++i) {
        const uint32_t w0 = p[i].x, w1 = p[i].y, w2 = p[i].z, w3 = p[i].w;
        // byte offset of dim d is 4*d: offA = (ia<<2) = (w&0xFFFE)<<1,
        // offB = (ib<<2) = (w>>15)&0x1FFFC. 8 independent reads batched.
        uint32_t A0 = ldw(rowi, (w0 & 0xFFFEu) << 1), B0 = ldw(rowi, (w0 >> 15) & 0x1FFFCu);
        uint32_t A1 = ldw(rowi, (w1 & 0xFFFEu) << 1), B1 = ldw(rowi, (w1 >> 15) & 0x1FFFCu);
        uint32_t A2 = ldw(rowi, (w2 & 0xFFFEu) << 1), B2 = ldw(rowi, (w2 >> 15) & 0x1FFFCu);
        uint32_t A3 = ldw(rowi, (w3 & 0xFFFEu) << 1), B3 = ldw(rowi, (w3 >> 15) & 0x1FFFCu);

        // packed select (both rows share the flag), then fp32 converts + muls
        h2 a0 = __builtin_bit_cast(h2, sel2(w0 & 1u, A0)), b0 = __builtin_bit_cast(h2, sel2(w0 & 0x10000u, B0));
        h2 a1 = __builtin_bit_cast(h2, sel2(w1 & 1u, A1)), b1 = __builtin_bit_cast(h2, sel2(w1 & 0x10000u, B1));
        h2 a2 = __builtin_bit_cast(h2, sel2(w2 & 1u, A2)), b2 = __builtin_bit_cast(h2, sel2(w2 & 0x10000u, B2));
        h2 a3 = __builtin_bit_cast(h2, sel2(w3 & 1u, A3)), b3 = __builtin_bit_cast(h2, sel2(w3 & 0x10000u, B3));

        fvec4 res0, res1;
        res0.x = (float)a0.x * (float)b0.x;  res1.x = (float)a0.y * (float)b0.y;
        res0.y = (float)a1.x * (float)b1.x;  res1.y = (float)a1.y * (float)b1.y;
        res0.z = (float)a2.x * (float)b2.x;  res1.z = (float)a2.y * (float)b2.y;
        res0.w = (float)a3.x * (float)b3.x;  res1.w = (float)a3.y * (float)b3.y;

        __builtin_nontemporal_store(res0, &o0[i * NT + t]);   // out never re-read
        __builtin_nontemporal_store(res1, &o1[i * NT + t]);
    }
}

extern "C" void kernel_launch(void* const* d_in, const int* in_sizes, int n_in,
                              void* d_out, int out_size, void* d_ws, size_t ws_size,
                              hipStream_t stream) {
    const float* x      = (const float*)d_in[0];
    const float* logits = (const float*)d_in[1];
    const int*   idx_a  = (const int*)d_in[2];
    const int*   idx_b  = (const int*)d_in[3];
    uint32_t*    packed = (uint32_t*)d_ws;   // 128 KiB scratch
    float*       out    = (float*)d_out;

    // allow 128 KiB dynamic LDS (one block per CU); idempotent, not a stream op
    static bool lds_opt_in = false;
    if (!lds_opt_in) {
        (void)hipFuncSetAttribute(reinterpret_cast<const void*>(logic_gather),
                                  hipFuncAttributeMaxDynamicSharedMemorySize, LDS_BYTES);
        lds_opt_in = true;
    }

    hipLaunchKernelGGL(pack_meta, dim3(OUT_DIM / 256), dim3(256), 0, stream,
                       idx_a, idx_b, logits, packed);
    hipLaunchKernelGGL(logic_gather, dim3(GRID), dim3(NT), LDS_BYTES, stream,
                       x, packed, out);
}